// Round 3
// baseline (363.865 us; speedup 1.0000x reference)
//
#include <hip/hip_runtime.h>

#define NN 100000
#define NE 3200000
#define DD 64

typedef unsigned int  uint32;
typedef unsigned short ushort16;

// ---------------------------------------------------------------------------
// bf16 round-to-nearest-even of an f32 (inputs are finite; no NaN handling).
// ---------------------------------------------------------------------------
__device__ inline uint32 bf16_rne(float f) {
    uint32 u = __float_as_uint(f);
    return (u + 0x7fffu + ((u >> 16) & 1u)) >> 16;
}

// ---------------------------------------------------------------------------
// Detect whether adj_row/adj_col were delivered as int64 (8B) or int32 (4B).
// If int64: int32 slots [NE/2, NE/2+1] hold {low word != 0, high word == 0}.
// If int32: both slots hold row values ~50000 != 0 (sorted, mid-array).
// ---------------------------------------------------------------------------
__global__ void detect_kernel(const void* rowbuf, int* flag) {
    const int* p = (const int*)rowbuf;
    int lo = p[NE / 2];
    int hi = p[NE / 2 + 1];
    *flag = (hi == 0 && lo != 0) ? 1 : 0;
}

// ---------------------------------------------------------------------------
// row_ptr[r] = lower_bound(adj_row, r); row r owns edges [rp[r], rp[r+1]).
// ---------------------------------------------------------------------------
__global__ void rowptr_kernel(const void* rowbuf, const int* __restrict__ flag,
                              int* __restrict__ rp) {
    int r = blockIdx.x * blockDim.x + threadIdx.x;
    if (r > NN) return;
    int is64 = *flag;
    int lo = 0, hi = NE;
    if (is64) {
        const long long* row = (const long long*)rowbuf;
        while (lo < hi) {
            int mid = (lo + hi) >> 1;
            if (row[mid] < (long long)r) lo = mid + 1; else hi = mid;
        }
    } else {
        const int* row = (const int*)rowbuf;
        while (lo < hi) {
            int mid = (lo + hi) >> 1;
            if (row[mid] < r) lo = mid + 1; else hi = mid;
        }
    }
    rp[r] = lo;
}

// ---------------------------------------------------------------------------
// f32 -> bf16 conversion, 8 elements/thread (n must be a multiple of 8).
// ---------------------------------------------------------------------------
__global__ void cvt_bf16_kernel(const float* __restrict__ X,
                                ushort16* __restrict__ Y, int n) {
    int i = (blockIdx.x * blockDim.x + threadIdx.x) * 8;
    if (i >= n) return;
    float4 a = *(const float4*)(X + i);
    float4 b = *(const float4*)(X + i + 4);
    uint4 o;
    o.x = bf16_rne(a.x) | (bf16_rne(a.y) << 16);
    o.y = bf16_rne(a.z) | (bf16_rne(a.w) << 16);
    o.z = bf16_rne(b.x) | (bf16_rne(b.y) << 16);
    o.w = bf16_rne(b.z) | (bf16_rne(b.w) << 16);
    *(uint4*)(Y + i) = o;
}

// ---------------------------------------------------------------------------
// acc[j] += v * bf16_row[sl*8 + j]   (8 bf16 packed in one uint4)
// ---------------------------------------------------------------------------
__device__ inline void accum8(float acc[8], uint4 g, float v) {
    uint32 u[4] = {g.x, g.y, g.z, g.w};
#pragma unroll
    for (int q = 0; q < 4; ++q) {
        float flo = __uint_as_float(u[q] << 16);
        float fhi = __uint_as_float(u[q] & 0xffff0000u);
        acc[2 * q]     = fmaf(v, flo, acc[2 * q]);
        acc[2 * q + 1] = fmaf(v, fhi, acc[2 * q + 1]);
    }
}

// ---------------------------------------------------------------------------
// Edge loop: 8 subgroups of 8 lanes; subgroup `sub` owns edges e0+sub,
// e0+sub+8, ...  Each lane gathers uint4 = 16B (8 lanes x 16B = one 128B
// bf16 row). Unrolled x2 -> up to 16 gathers in flight per wave.
// col/val are streamed nontemporally (don't evict support from L2).
// ---------------------------------------------------------------------------
template <typename CT>
__device__ inline void edge_loop(const uint4* __restrict__ Xq,
                                 const CT* __restrict__ col,
                                 const float* __restrict__ val,
                                 int e0, int e1, int sub, int sl,
                                 float acc[8]) {
    int e = e0 + sub;
    for (; e + 8 < e1; e += 16) {
        int   c0 = (int)__builtin_nontemporal_load(&col[e]);
        float v0 = __builtin_nontemporal_load(&val[e]);
        int   c1 = (int)__builtin_nontemporal_load(&col[e + 8]);
        float v1 = __builtin_nontemporal_load(&val[e + 8]);
        uint4 g0 = Xq[(size_t)c0 * 8 + sl];
        uint4 g1 = Xq[(size_t)c1 * 8 + sl];
        accum8(acc, g0, v0);
        accum8(acc, g1, v1);
    }
    if (e < e1) {
        int   c = (int)__builtin_nontemporal_load(&col[e]);
        float v = __builtin_nontemporal_load(&val[e]);
        uint4 g = Xq[(size_t)c * 8 + sl];
        accum8(acc, g, v);
    }
}

// ---------------------------------------------------------------------------
// Fused GCN layer on bf16 support:
//   out[row,:] = act( (sum_e val[e]*Xb[col[e],:]) @ W + b )
// One wave per row. After subgroup reduction, feature k lives in lane (k>>3)
// register acc[k&7]; W-multiply is 64 shfl-broadcast + LDS FMA
// (sW[k*64+lane]: 2-way bank aliasing = free).
// ---------------------------------------------------------------------------
template <bool OUT_BF16>
__global__ __launch_bounds__(256) void fused_layer_kernel(
    const ushort16* __restrict__ Xb, const void* colbuf,
    const float* __restrict__ val, const int* __restrict__ rp,
    const int* __restrict__ flag, const float* __restrict__ W,
    const float* __restrict__ bias, void* __restrict__ outv, int leaky) {
    __shared__ float sW[DD * DD];
    for (int i = threadIdx.x; i < DD * DD; i += blockDim.x) sW[i] = W[i];
    __syncthreads();

    int wave = threadIdx.x >> 6;
    int lane = threadIdx.x & 63;
    int row  = blockIdx.x * (blockDim.x >> 6) + wave;
    if (row >= NN) return;

    int sub = lane >> 3;  // 0..7 edge slot
    int sl  = lane & 7;   // 0..7 feature octet
    int e0 = rp[row], e1 = rp[row + 1];

    const uint4* Xq = (const uint4*)Xb;  // row c = Xq[c*8 .. c*8+7]
    float acc[8] = {0.f, 0.f, 0.f, 0.f, 0.f, 0.f, 0.f, 0.f};

    if (*flag) {
        edge_loop(Xq, (const long long*)colbuf, val, e0, e1, sub, sl, acc);
    } else {
        edge_loop(Xq, (const int*)colbuf, val, e0, e1, sub, sl, acc);
    }

    // reduce across the 8 subgroups -> every lane holds h[sl*8 + j] in acc[j]
#pragma unroll
    for (int j = 0; j < 8; ++j) {
        acc[j] += __shfl_xor(acc[j], 8);
        acc[j] += __shfl_xor(acc[j], 16);
        acc[j] += __shfl_xor(acc[j], 32);
    }

    // y[lane] = b[lane] + sum_k h[k] * W[k][lane];  h[k] from lane (k>>3)
    float y = bias[lane];
#pragma unroll
    for (int k = 0; k < DD; ++k) {
        float h = __shfl(acc[k & 7], k >> 3, 64);
        y = fmaf(h, sW[k * DD + lane], y);
    }

    if (leaky) y = (y >= 0.f) ? y : 0.2f * y;

    if (OUT_BF16) {
        ushort16* o = (ushort16*)outv;
        o[(size_t)row * DD + lane] = (ushort16)bf16_rne(y);
    } else {
        float* o = (float*)outv;
        __builtin_nontemporal_store(y, &o[(size_t)row * DD + lane]);
    }
}

// ---------------------------------------------------------------------------
extern "C" void kernel_launch(void* const* d_in, const int* in_sizes, int n_in,
                              void* d_out, int out_size, void* d_ws, size_t ws_size,
                              hipStream_t stream) {
    const float* x       = (const float*)d_in[0];
    const void*  adj_row = d_in[1];
    const void*  adj_col = d_in[2];
    const float* adj_val = (const float*)d_in[3];
    const float* W1      = (const float*)d_in[4];
    const float* b1      = (const float*)d_in[5];
    const float* W2      = (const float*)d_in[6];
    const float* b2      = (const float*)d_in[7];
    float*       out     = (float*)d_out;

    // workspace: xb [NN*DD bf16] | hb [NN*DD bf16] | row_ptr [NN+1] | flag
    ushort16* xb  = (ushort16*)d_ws;
    ushort16* hb  = xb + (size_t)NN * DD;
    int*      rp  = (int*)(hb + (size_t)NN * DD);
    int*      flag = rp + (NN + 1);

    detect_kernel<<<1, 1, 0, stream>>>(adj_row, flag);
    rowptr_kernel<<<(NN + 1 + 255) / 256, 256, 0, stream>>>(adj_row, flag, rp);

    const int n = NN * DD;
    cvt_bf16_kernel<<<(n / 8 + 255) / 256, 256, 0, stream>>>(x, xb, n);

    const int grid = (NN + 3) / 4;  // 4 waves (rows) per 256-thread block

    // layer 1: hb = bf16( LeakyReLU( (A xb) W1 + b1 ) )
    fused_layer_kernel<true><<<grid, 256, 0, stream>>>(
        xb, adj_col, adj_val, rp, flag, W1, b1, hb, 1);
    // layer 2: out = (A hb) W2 + b2   (f32)
    fused_layer_kernel<false><<<grid, 256, 0, stream>>>(
        hb, adj_col, adj_val, rp, flag, W2, b2, out, 0);
}

// Round 4
// 335.705 us; speedup vs baseline: 1.0839x; 1.0839x over previous
//
#include <hip/hip_runtime.h>

#define NN 100000
#define NE 3200000
#define DD 64

typedef unsigned int  uint32;
typedef unsigned short ushort16;

// ---------------------------------------------------------------------------
// bf16 round-to-nearest-even of an f32 (inputs are finite; no NaN handling).
// ---------------------------------------------------------------------------
__device__ inline uint32 bf16_rne(float f) {
    uint32 u = __float_as_uint(f);
    return (u + 0x7fffu + ((u >> 16) & 1u)) >> 16;
}

// ---------------------------------------------------------------------------
// Detect whether adj_row/adj_col were delivered as int64 (8B) or int32 (4B).
// If int64: int32 slots [NE/2, NE/2+1] hold {low word != 0, high word == 0}.
// If int32: both slots hold row values ~50000 != 0 (sorted, mid-array).
// ---------------------------------------------------------------------------
__global__ void detect_kernel(const void* rowbuf, int* flag) {
    const int* p = (const int*)rowbuf;
    int lo = p[NE / 2];
    int hi = p[NE / 2 + 1];
    *flag = (hi == 0 && lo != 0) ? 1 : 0;
}

// ---------------------------------------------------------------------------
// row_ptr[r] = lower_bound(adj_row, r); row r owns edges [rp[r], rp[r+1]).
// ---------------------------------------------------------------------------
__global__ void rowptr_kernel(const void* rowbuf, const int* __restrict__ flag,
                              int* __restrict__ rp) {
    int r = blockIdx.x * blockDim.x + threadIdx.x;
    if (r > NN) return;
    int is64 = *flag;
    int lo = 0, hi = NE;
    if (is64) {
        const long long* row = (const long long*)rowbuf;
        while (lo < hi) {
            int mid = (lo + hi) >> 1;
            if (row[mid] < (long long)r) lo = mid + 1; else hi = mid;
        }
    } else {
        const int* row = (const int*)rowbuf;
        while (lo < hi) {
            int mid = (lo + hi) >> 1;
            if (row[mid] < r) lo = mid + 1; else hi = mid;
        }
    }
    rp[r] = lo;
}

// ---------------------------------------------------------------------------
// f32 -> bf16 conversion, 8 elements/thread (n must be a multiple of 8).
// ---------------------------------------------------------------------------
__global__ void cvt_bf16_kernel(const float* __restrict__ X,
                                ushort16* __restrict__ Y, int n) {
    int i = (blockIdx.x * blockDim.x + threadIdx.x) * 8;
    if (i >= n) return;
    float4 a = *(const float4*)(X + i);
    float4 b = *(const float4*)(X + i + 4);
    uint4 o;
    o.x = bf16_rne(a.x) | (bf16_rne(a.y) << 16);
    o.y = bf16_rne(a.z) | (bf16_rne(a.w) << 16);
    o.z = bf16_rne(b.x) | (bf16_rne(b.y) << 16);
    o.w = bf16_rne(b.z) | (bf16_rne(b.w) << 16);
    *(uint4*)(Y + i) = o;
}

// ---------------------------------------------------------------------------
// acc[j] += v * bf16_row[sl*8 + j]   (8 bf16 packed in one uint4)
// ---------------------------------------------------------------------------
__device__ inline void accum8(float acc[8], uint4 g, float v) {
    uint32 u[4] = {g.x, g.y, g.z, g.w};
#pragma unroll
    for (int q = 0; q < 4; ++q) {
        float flo = __uint_as_float(u[q] << 16);
        float fhi = __uint_as_float(u[q] & 0xffff0000u);
        acc[2 * q]     = fmaf(v, flo, acc[2 * q]);
        acc[2 * q + 1] = fmaf(v, fhi, acc[2 * q + 1]);
    }
}

// ---------------------------------------------------------------------------
// Edge loop: 8 subgroups of 8 lanes; subgroup `sub` owns edges e0+sub,
// e0+sub+8, ...  Each lane gathers uint4 = 16B (8 lanes x 16B = one 128B
// bf16 row). Explicit 4-deep load-then-use structure: 4 col/val loads, then
// 4 row gathers, then 4 accumulations -> 32 edges in flight per wave.
// ---------------------------------------------------------------------------
template <typename CT>
__device__ inline void edge_loop(const uint4* __restrict__ Xq,
                                 const CT* __restrict__ col,
                                 const float* __restrict__ val,
                                 int e0, int e1, int sub, int sl,
                                 float acc[8]) {
    int e = e0 + sub;
    for (; e + 24 < e1; e += 32) {
        int   c0 = (int)col[e];      float v0 = val[e];
        int   c1 = (int)col[e + 8];  float v1 = val[e + 8];
        int   c2 = (int)col[e + 16]; float v2 = val[e + 16];
        int   c3 = (int)col[e + 24]; float v3 = val[e + 24];
        uint4 g0 = Xq[(size_t)c0 * 8 + sl];
        uint4 g1 = Xq[(size_t)c1 * 8 + sl];
        uint4 g2 = Xq[(size_t)c2 * 8 + sl];
        uint4 g3 = Xq[(size_t)c3 * 8 + sl];
        accum8(acc, g0, v0);
        accum8(acc, g1, v1);
        accum8(acc, g2, v2);
        accum8(acc, g3, v3);
    }
    for (; e < e1; e += 8) {
        int c = (int)col[e]; float v = val[e];
        uint4 g = Xq[(size_t)c * 8 + sl];
        accum8(acc, g, v);
    }
}

// ---------------------------------------------------------------------------
// Fused GCN layer on bf16 support:
//   out[row,:] = act( (sum_e val[e]*Xb[col[e],:]) @ W + b )
// One wave per row. After subgroup reduction, feature k lives in lane (k>>3)
// register acc[k&7]; W-multiply uses 4 independent accumulator chains so the
// unrolled loop can batch ds_reads/readlanes instead of a 64-deep serial
// chain. __launch_bounds__(256,2) lifts the VGPR cap to 128 (round-3 build
// got squeezed to 20 VGPRs -> zero memory-level parallelism).
// ---------------------------------------------------------------------------
template <bool OUT_BF16>
__global__ __launch_bounds__(256, 2) void fused_layer_kernel(
    const ushort16* __restrict__ Xb, const void* colbuf,
    const float* __restrict__ val, const int* __restrict__ rp,
    const int* __restrict__ flag, const float* __restrict__ W,
    const float* __restrict__ bias, void* __restrict__ outv, int leaky) {
    __shared__ float sW[DD * DD];
    for (int i = threadIdx.x; i < DD * DD; i += blockDim.x) sW[i] = W[i];
    __syncthreads();

    int wave = threadIdx.x >> 6;
    int lane = threadIdx.x & 63;
    int row  = blockIdx.x * (blockDim.x >> 6) + wave;
    if (row >= NN) return;

    int sub = lane >> 3;  // 0..7 edge slot
    int sl  = lane & 7;   // 0..7 feature octet
    int e0 = rp[row], e1 = rp[row + 1];

    const uint4* Xq = (const uint4*)Xb;  // row c = Xq[c*8 .. c*8+7]
    float acc[8] = {0.f, 0.f, 0.f, 0.f, 0.f, 0.f, 0.f, 0.f};

    if (*flag) {
        edge_loop(Xq, (const long long*)colbuf, val, e0, e1, sub, sl, acc);
    } else {
        edge_loop(Xq, (const int*)colbuf, val, e0, e1, sub, sl, acc);
    }

    // reduce across the 8 subgroups -> every lane holds h[sl*8 + j] in acc[j]
#pragma unroll
    for (int j = 0; j < 8; ++j) {
        acc[j] += __shfl_xor(acc[j], 8);
        acc[j] += __shfl_xor(acc[j], 16);
        acc[j] += __shfl_xor(acc[j], 32);
    }

    // y[lane] = b[lane] + sum_k h[k] * W[k][lane];  h[k] from lane (k>>3).
    // 4 independent chains; after unroll all shfl/ds_read are batchable.
    float y0 = bias[lane], y1 = 0.f, y2 = 0.f, y3 = 0.f;
#pragma unroll
    for (int k4 = 0; k4 < 16; ++k4) {
        int k = k4 * 4;
        float h0 = __shfl(acc[(k + 0) & 7], (k + 0) >> 3, 64);
        float h1 = __shfl(acc[(k + 1) & 7], (k + 1) >> 3, 64);
        float h2 = __shfl(acc[(k + 2) & 7], (k + 2) >> 3, 64);
        float h3 = __shfl(acc[(k + 3) & 7], (k + 3) >> 3, 64);
        y0 = fmaf(h0, sW[(k + 0) * DD + lane], y0);
        y1 = fmaf(h1, sW[(k + 1) * DD + lane], y1);
        y2 = fmaf(h2, sW[(k + 2) * DD + lane], y2);
        y3 = fmaf(h3, sW[(k + 3) * DD + lane], y3);
    }
    float y = (y0 + y1) + (y2 + y3);

    if (leaky) y = (y >= 0.f) ? y : 0.2f * y;

    if (OUT_BF16) {
        ushort16* o = (ushort16*)outv;
        o[(size_t)row * DD + lane] = (ushort16)bf16_rne(y);
    } else {
        float* o = (float*)outv;
        __builtin_nontemporal_store(y, &o[(size_t)row * DD + lane]);
    }
}

// ---------------------------------------------------------------------------
extern "C" void kernel_launch(void* const* d_in, const int* in_sizes, int n_in,
                              void* d_out, int out_size, void* d_ws, size_t ws_size,
                              hipStream_t stream) {
    const float* x       = (const float*)d_in[0];
    const void*  adj_row = d_in[1];
    const void*  adj_col = d_in[2];
    const float* adj_val = (const float*)d_in[3];
    const float* W1      = (const float*)d_in[4];
    const float* b1      = (const float*)d_in[5];
    const float* W2      = (const float*)d_in[6];
    const float* b2      = (const float*)d_in[7];
    float*       out     = (float*)d_out;

    // workspace: xb [NN*DD bf16] | hb [NN*DD bf16] | row_ptr [NN+1] | flag
    ushort16* xb  = (ushort16*)d_ws;
    ushort16* hb  = xb + (size_t)NN * DD;
    int*      rp  = (int*)(hb + (size_t)NN * DD);
    int*      flag = rp + (NN + 1);

    detect_kernel<<<1, 1, 0, stream>>>(adj_row, flag);
    rowptr_kernel<<<(NN + 1 + 255) / 256, 256, 0, stream>>>(adj_row, flag, rp);

    const int n = NN * DD;
    cvt_bf16_kernel<<<(n / 8 + 255) / 256, 256, 0, stream>>>(x, xb, n);

    const int grid = (NN + 3) / 4;  // 4 waves (rows) per 256-thread block

    // layer 1: hb = bf16( LeakyReLU( (A xb) W1 + b1 ) )
    fused_layer_kernel<true><<<grid, 256, 0, stream>>>(
        xb, adj_col, adj_val, rp, flag, W1, b1, hb, 1);
    // layer 2: out = (A hb) W2 + b2   (f32)
    fused_layer_kernel<false><<<grid, 256, 0, stream>>>(
        hb, adj_col, adj_val, rp, flag, W2, b2, out, 0);
}

// Round 5
// 249.718 us; speedup vs baseline: 1.4571x; 1.3443x over previous
//
#include <hip/hip_runtime.h>

#define NN 100000
#define NE 3200000
#define DD 64
#define K_EDGES 64   // edges per half-wave worker (NE % K_EDGES == 0)

typedef unsigned int uint32;

// ---------------------------------------------------------------------------
// bf16 round-to-nearest-even of an f32 (inputs finite).
// ---------------------------------------------------------------------------
__device__ inline uint32 bf16_rne(float f) {
    uint32 u = __float_as_uint(f);
    return (u + 0x7fffu + ((u >> 16) & 1u)) >> 16;
}

// ---------------------------------------------------------------------------
// int64 vs int32 index detection (see round-1 notes).
// ---------------------------------------------------------------------------
__global__ void detect_kernel(const void* rowbuf, int* flag) {
    const int* p = (const int*)rowbuf;
    int lo = p[NE / 2];
    int hi = p[NE / 2 + 1];
    *flag = (hi == 0 && lo != 0) ? 1 : 0;
}

// ---------------------------------------------------------------------------
__global__ void zero_kernel(uint4* __restrict__ p, int n4) {
    int i = blockIdx.x * blockDim.x + threadIdx.x;
    if (i < n4) p[i] = make_uint4(0u, 0u, 0u, 0u);
}

// ---------------------------------------------------------------------------
// f32 -> packed bf16 (uint = 2 features), 8 elements/thread.
// ---------------------------------------------------------------------------
__global__ void cvt_bf16_kernel(const float* __restrict__ X,
                                uint32* __restrict__ Y, int n) {
    int i = (blockIdx.x * blockDim.x + threadIdx.x) * 8;
    if (i >= n) return;
    float4 a = *(const float4*)(X + i);
    float4 b = *(const float4*)(X + i + 4);
    uint4 o;
    o.x = bf16_rne(a.x) | (bf16_rne(a.y) << 16);
    o.y = bf16_rne(a.z) | (bf16_rne(a.w) << 16);
    o.z = bf16_rne(b.x) | (bf16_rne(b.y) << 16);
    o.w = bf16_rne(b.z) | (bf16_rne(b.w) << 16);
    *(uint4*)(Y + i / 2) = o;
}

// ---------------------------------------------------------------------------
// Edge-parallel SpMM worker: half-wave (32 lanes) streams K_EDGES sorted
// edges. Lane sl holds features {2sl, 2sl+1} (one uint = 2 bf16). Gathers are
// double-buffered 8-deep (g0..g7 / h0..h7, all static names). Row-carry
// accumulate in (ax, ay); flush on row change via f32 atomicAdd (rows sorted
// -> ~1 flush per degree(32) edges; chunk-boundary rows merge via atomics).
// ---------------------------------------------------------------------------
#define ISSUE(G, I) {                                   \
    int ci_ = __shfl(c, (I), 32);                       \
    G = Xq[(size_t)(uint32)ci_ * 32u + (uint32)sl]; }

#define ACCUM(G, I) {                                   \
    int   ri_ = __shfl(r, (I), 32);                     \
    float vi_ = __shfl(v, (I), 32);                     \
    if (ri_ != rc) {                                    \
        if (rc >= 0) {                                  \
            atomicAdd(out + (size_t)rc * DD + 2 * sl,     ax); \
            atomicAdd(out + (size_t)rc * DD + 2 * sl + 1, ay); \
        }                                               \
        ax = 0.f; ay = 0.f; rc = ri_;                   \
    }                                                   \
    float lo_ = __uint_as_float(G << 16);               \
    float hi_ = __uint_as_float(G & 0xffff0000u);       \
    ax = fmaf(vi_, lo_, ax); ay = fmaf(vi_, hi_, ay); }

template <typename IT>
__device__ inline void spmm_worker(const uint32* __restrict__ Xq,
                                   const IT* __restrict__ rowA,
                                   const IT* __restrict__ colA,
                                   const float* __restrict__ valA,
                                   float* __restrict__ out,
                                   long long s, int sl) {
    float ax = 0.f, ay = 0.f;
    int rc = -1;
#pragma unroll
    for (int b = 0; b < K_EDGES / 32; ++b) {
        long long e = s + b * 32 + sl;
        int   c = (int)colA[e];
        int   r = (int)rowA[e];
        float v = valA[e];
        uint32 g0, g1, g2, g3, g4, g5, g6, g7;
        uint32 h0, h1, h2, h3, h4, h5, h6, h7;
        ISSUE(g0, 0)  ISSUE(g1, 1)  ISSUE(g2, 2)  ISSUE(g3, 3)
        ISSUE(g4, 4)  ISSUE(g5, 5)  ISSUE(g6, 6)  ISSUE(g7, 7)
        ISSUE(h0, 8)  ISSUE(h1, 9)  ISSUE(h2, 10) ISSUE(h3, 11)
        ISSUE(h4, 12) ISSUE(h5, 13) ISSUE(h6, 14) ISSUE(h7, 15)
        ACCUM(g0, 0)  ACCUM(g1, 1)  ACCUM(g2, 2)  ACCUM(g3, 3)
        ACCUM(g4, 4)  ACCUM(g5, 5)  ACCUM(g6, 6)  ACCUM(g7, 7)
        ISSUE(g0, 16) ISSUE(g1, 17) ISSUE(g2, 18) ISSUE(g3, 19)
        ISSUE(g4, 20) ISSUE(g5, 21) ISSUE(g6, 22) ISSUE(g7, 23)
        ACCUM(h0, 8)  ACCUM(h1, 9)  ACCUM(h2, 10) ACCUM(h3, 11)
        ACCUM(h4, 12) ACCUM(h5, 13) ACCUM(h6, 14) ACCUM(h7, 15)
        ISSUE(h0, 24) ISSUE(h1, 25) ISSUE(h2, 26) ISSUE(h3, 27)
        ISSUE(h4, 28) ISSUE(h5, 29) ISSUE(h6, 30) ISSUE(h7, 31)
        ACCUM(g0, 16) ACCUM(g1, 17) ACCUM(g2, 18) ACCUM(g3, 19)
        ACCUM(g4, 20) ACCUM(g5, 21) ACCUM(g6, 22) ACCUM(g7, 23)
        ACCUM(h0, 24) ACCUM(h1, 25) ACCUM(h2, 26) ACCUM(h3, 27)
        ACCUM(h4, 28) ACCUM(h5, 29) ACCUM(h6, 30) ACCUM(h7, 31)
    }
    if (rc >= 0) {
        atomicAdd(out + (size_t)rc * DD + 2 * sl,     ax);
        atomicAdd(out + (size_t)rc * DD + 2 * sl + 1, ay);
    }
}

__global__ __launch_bounds__(256) void spmm_kernel(
    const uint32* __restrict__ Xq, const void* rowbuf, const void* colbuf,
    const float* __restrict__ valA, const int* __restrict__ flag,
    float* __restrict__ out) {
    int worker = (blockIdx.x * blockDim.x + threadIdx.x) >> 5;
    int sl = threadIdx.x & 31;
    long long s = (long long)worker * K_EDGES;
    if (s >= NE) return;
    if (*flag)
        spmm_worker<long long>(Xq, (const long long*)rowbuf,
                               (const long long*)colbuf, valA, out, s, sl);
    else
        spmm_worker<int>(Xq, (const int*)rowbuf, (const int*)colbuf, valA,
                         out, s, sl);
}

// ---------------------------------------------------------------------------
// Dense per-node GEMM:  y[row,:] = act(B[row,:] @ W + b).  One thread per
// node, 64 f32 accumulators, W staged in LDS as float4 (all lanes read the
// same address -> broadcast, conflict-free). OUT_BF16 packs 2 bf16/uint for
// the next layer's gathers; else writes f32 (in-place on B is safe: each
// thread reads only its own row before overwriting it).
// ---------------------------------------------------------------------------
template <bool OUT_BF16>
__global__ __launch_bounds__(256) void gemm_kernel(
    const float* __restrict__ B, const float* __restrict__ W,
    const float* __restrict__ bias, void* __restrict__ outv, int leaky) {
    __shared__ float4 sW[DD * 16];   // sW[k*16 + j4] = W[k][4j4 .. 4j4+3]
    __shared__ float  sb[DD];
    for (int i = threadIdx.x; i < DD * 16; i += 256)
        sW[i] = ((const float4*)W)[i];
    if (threadIdx.x < DD) sb[threadIdx.x] = bias[threadIdx.x];
    __syncthreads();

    int row = blockIdx.x * 256 + threadIdx.x;
    if (row >= NN) return;

    float acc[DD];
#pragma unroll
    for (int j = 0; j < DD; ++j) acc[j] = sb[j];

    const float4* Bp = (const float4*)(B + (size_t)row * DD);
#pragma unroll
    for (int k4 = 0; k4 < 16; ++k4) {
        float4 x4 = Bp[k4];
        float xs[4] = {x4.x, x4.y, x4.z, x4.w};
#pragma unroll
        for (int kk = 0; kk < 4; ++kk) {
            float xk = xs[kk];
            int k = 4 * k4 + kk;
#pragma unroll
            for (int j4 = 0; j4 < 16; ++j4) {
                float4 w = sW[k * 16 + j4];
                acc[4 * j4 + 0] = fmaf(xk, w.x, acc[4 * j4 + 0]);
                acc[4 * j4 + 1] = fmaf(xk, w.y, acc[4 * j4 + 1]);
                acc[4 * j4 + 2] = fmaf(xk, w.z, acc[4 * j4 + 2]);
                acc[4 * j4 + 3] = fmaf(xk, w.w, acc[4 * j4 + 3]);
            }
        }
    }

    if (leaky) {
#pragma unroll
        for (int j = 0; j < DD; ++j)
            acc[j] = (acc[j] >= 0.f) ? acc[j] : 0.2f * acc[j];
    }

    if (OUT_BF16) {
        uint32* o = (uint32*)outv + (size_t)row * 32;
#pragma unroll
        for (int q = 0; q < 32; ++q)
            o[q] = bf16_rne(acc[2 * q]) | (bf16_rne(acc[2 * q + 1]) << 16);
    } else {
        float* o = (float*)outv + (size_t)row * DD;
#pragma unroll
        for (int j = 0; j < DD; ++j) o[j] = acc[j];
    }
}

// ---------------------------------------------------------------------------
extern "C" void kernel_launch(void* const* d_in, const int* in_sizes, int n_in,
                              void* d_out, int out_size, void* d_ws, size_t ws_size,
                              hipStream_t stream) {
    const float* x       = (const float*)d_in[0];
    const void*  adj_row = d_in[1];
    const void*  adj_col = d_in[2];
    const float* adj_val = (const float*)d_in[3];
    const float* W1      = (const float*)d_in[4];
    const float* b1      = (const float*)d_in[5];
    const float* W2      = (const float*)d_in[6];
    const float* b2      = (const float*)d_in[7];
    float*       out     = (float*)d_out;

    // ws: B1 [NN*DD f32] | xb [NN*DD bf16 packed] | hb [NN*DD bf16] | flag
    float*  B1   = (float*)d_ws;
    uint32* xb   = (uint32*)(B1 + (size_t)NN * DD);           // NN*32 uints
    uint32* hb   = xb + (size_t)NN * 32;
    int*    flag = (int*)(hb + (size_t)NN * 32);

    detect_kernel<<<1, 1, 0, stream>>>(adj_row, flag);

    const int n4 = NN * DD / 4;
    zero_kernel<<<(n4 + 255) / 256, 256, 0, stream>>>((uint4*)B1, n4);
    zero_kernel<<<(n4 + 255) / 256, 256, 0, stream>>>((uint4*)out, n4);

    const int n = NN * DD;
    cvt_bf16_kernel<<<(n / 8 + 255) / 256, 256, 0, stream>>>(x, xb, n);

    const int spmm_blocks = (NE / K_EDGES) * 32 / 256;   // 6250
    const int gemm_blocks = (NN + 255) / 256;            // 391

    // layer 1: B1 = A xb ; hb = bf16(LeakyReLU(B1 W1 + b1))
    spmm_kernel<<<spmm_blocks, 256, 0, stream>>>(xb, adj_row, adj_col, adj_val,
                                                 flag, B1);
    gemm_kernel<true><<<gemm_blocks, 256, 0, stream>>>(B1, W1, b1, hb, 1);

    // layer 2: out = A hb ; out = out W2 + b2 (in place)
    spmm_kernel<<<spmm_blocks, 256, 0, stream>>>(hb, adj_row, adj_col, adj_val,
                                                 flag, out);
    gemm_kernel<false><<<gemm_blocks, 256, 0, stream>>>(out, W2, b2, out, 0);
}